// Round 3
// baseline (589.661 us; speedup 1.0000x reference)
//
#include <hip/hip_runtime.h>
#include <hip/hip_bf16.h>

typedef __bf16 bf16x8 __attribute__((ext_vector_type(8)));
typedef __bf16 bf16x4 __attribute__((ext_vector_type(4)));
typedef float  f32x4  __attribute__((ext_vector_type(4)));
typedef float  f32x16 __attribute__((ext_vector_type(16)));

#define B_    64
#define CIN   64
#define HIN   64
#define WIN   64
#define COUT  128
#define HO    62
#define WO    62
#define NPIX  (B_*HO*WO)        /* 246016 = 1922*128 exactly */
#define NITER 13                /* LDS rounds; +1 final matvec = 14 total */

// ---------------------------------------------------------------------------
// prep_w: W_ff -> wt[tap][o][c] bf16 ; W_rec -> wr[o][c] = NEGATED bf16
// (negated so iterate's MFMA computes u0f + (-Wr)a with acc init = u0f,
//  eliminating 32 v_sub per iteration)
// ---------------------------------------------------------------------------
__global__ void prep_w_kernel(const float* __restrict__ wff,
                              const float* __restrict__ wrec,
                              __bf16* __restrict__ wt,
                              __bf16* __restrict__ wr) {
  int i = blockIdx.x * 256 + threadIdx.x;
  const int NW = 9 * COUT * CIN;            // 73728
  if (i < NW) {
    int tap = i / (COUT * CIN);
    int rem = i % (COUT * CIN);
    int o = rem >> 6;                       // /CIN
    int c = rem & 63;
    int kh = tap / 3, kw = tap % 3;
    wt[i] = (__bf16)wff[((o * CIN + c) * 3 + kh) * 3 + kw];
  } else {
    int j = i - NW;
    if (j < COUT * COUT) wr[j] = (__bf16)(-wrec[j]);
  }
}

// ---------------------------------------------------------------------------
// prep_x: x NCHW fp32 -> bf16, layout [b][h][c>>3][w][c&7]
// ---------------------------------------------------------------------------
__global__ void prep_x_kernel(const float* __restrict__ x,
                              __bf16* __restrict__ xh) {
  __shared__ float t[64][65];               // pad -> conflict-free transpose
  int tid = threadIdx.x;
  int b = blockIdx.x >> 6;
  int h = blockIdx.x & 63;
#pragma unroll
  for (int it = 0; it < 16; ++it) {         // read coalesced over w
    int c = it * 4 + (tid >> 6);
    int w = tid & 63;
    t[c][w] = x[(((size_t)(b * 64 + c)) * 64 + h) * 64 + w];
  }
  __syncthreads();
  size_t rowbase = (size_t)blockIdx.x * 4096;
#pragma unroll
  for (int it = 0; it < 16; ++it) {         // write contiguous
    int j = it * 256 + tid;                 // 0..4095
    int c8  = j & 7;
    int w   = (j >> 3) & 63;
    int grp = j >> 9;
    xh[rowbase + j] = (__bf16)t[grp * 8 + c8][w];
  }
}

// ---------------------------------------------------------------------------
// conv: persistent-weight implicit GEMM, 32x32x16 bf16 MFMA.
// sched_group_barrier pins 4xDS-read : 4xMFMA per tap so the scheduler
// cannot hoist all 36 B-frags (which blew past 256 VGPR -> spill in R2).
// ---------------------------------------------------------------------------
__global__ __launch_bounds__(256, 2) void conv_kernel(
    const __bf16* __restrict__ xh, const __bf16* __restrict__ wt,
    float* __restrict__ u0) {
  // layout [row 6][grp 8][w 64][c8 8] = 24576 el = 48KB, flat == global order
  __shared__ __align__(16) __bf16 xs[6 * 8 * 64 * 8];
  int tid  = threadIdx.x;
  int lane = tid & 63;
  int wv   = tid >> 6;                      // 0..3 : c_out slice
  int hg   = blockIdx.x;                    // 0..15 : output-row group (4 rows)
  int b    = blockIdx.y;

  // ---- stage 6 input rows (hg*4 .. hg*4+5, clamped) ----
#pragma unroll
  for (int i = 0; i < 12; ++i) {
    int chunk = wv * 12 + i;                // 0..47
    int row = chunk >> 3;                   // local row 0..5
    int part = chunk & 7;                   // 1KB part within 8KB row
    int row_src = hg * 4 + row;
    if (row_src > 63) row_src = 63;         // hg=15 halo clamp (unused outputs)
    const __bf16* g = xh + ((size_t)(b * 64 + row_src)) * 4096 + part * 512 + lane * 8;
    __bf16* l = xs + chunk * 512;           // HW adds lane*16 bytes
    __builtin_amdgcn_global_load_lds(
        (const __attribute__((address_space(1))) void*)g,
        (__attribute__((address_space(3))) void*)l, 16, 0, 0);
  }

  // ---- this wave's full weight set -> registers (144 VGPRs, loaded once) ----
  int m31 = lane & 31;
  int khalf = lane >> 5;                    // A[m][k]: m=lane&31, k=khalf*8+j
  bf16x8 Wf[36];
#pragma unroll
  for (int tap = 0; tap < 9; ++tap)
#pragma unroll
    for (int k4 = 0; k4 < 4; ++k4)
      Wf[tap * 4 + k4] = *(const bf16x8*)
          &wt[((size_t)tap * COUT + wv * 32 + m31) * CIN + k4 * 16 + khalf * 8];

  __syncthreads();

  // ---- 8 n-tiles of 32 pixels ----
#pragma unroll 1
  for (int nt = 0; nt < 8; ++nt) {
    int px = nt * 32 + m31;                 // local pixel 0..255 (248 valid)
    int r = (px >= 62) + (px >= 124) + (px >= 186) + (px >= 248);
    if (r > 3) r = 3;
    int wcol = px - r * 62;
    if (wcol > 61) wcol = 61;
    int orow = hg * 4 + r;
    bool valid = (px < 248) && (orow < 62);
    const char* lbase = (const char*)xs + (((r * 8 + khalf) * 64 + wcol) << 4);

    f32x16 acc0, acc1;
#pragma unroll
    for (int q = 0; q < 16; ++q) { acc0[q] = 0.f; acc1[q] = 0.f; }

#pragma unroll
    for (int tap = 0; tap < 9; ++tap) {
      int kh = tap / 3, kw = tap % 3;
#pragma unroll
      for (int k4 = 0; k4 < 4; ++k4) {
        bf16x8 Bf = *(const bf16x8*)(lbase + kh * 8192 + k4 * 2048 + kw * 16);
        int idx = tap * 4 + k4;
        if (idx & 1) acc1 = __builtin_amdgcn_mfma_f32_32x32x16_bf16(Wf[idx], Bf, acc1, 0, 0, 0);
        else         acc0 = __builtin_amdgcn_mfma_f32_32x32x16_bf16(Wf[idx], Bf, acc0, 0, 0, 0);
      }
    }
    // pin schedule: 4 DS-reads then 4 MFMAs, 9x -> caps B-frag lookahead
#pragma unroll
    for (int tap = 0; tap < 9; ++tap) {
      __builtin_amdgcn_sched_group_barrier(0x100, 4, 0);  // DS read
      __builtin_amdgcn_sched_group_barrier(0x008, 4, 0);  // MFMA
    }
    if (valid) {
      size_t pix = ((size_t)b * HO + orow) * WO + wcol;
      // C/D layout 32x32: col=lane&31, row=(reg&3)+8*(reg>>2)+4*khalf
      float* up = u0 + pix * COUT + wv * 32 + khalf * 4;
#pragma unroll
      for (int g4 = 0; g4 < 4; ++g4) {
        f32x4 v;
#pragma unroll
        for (int q = 0; q < 4; ++q) v[q] = acc0[g4 * 4 + q] + acc1[g4 * 4 + q];
        *(f32x4*)&up[g4 * 8] = v;
      }
    }
  }
}

// ---------------------------------------------------------------------------
// iterate v3: 14 undamped Picard steps on-chip; 256 thr = 4 waves;
// each wave owns 2 independent 16-px tiles (ILP: tile B's MFMAs overlap
// tile A's DS round-trip). Wr stored negated -> acc init u0f, no subs.
// No barriers: wave reads/writes only its own 32 LDS rows.
// ---------------------------------------------------------------------------
__global__ __launch_bounds__(256, 3) void iterate_kernel(
    const float* __restrict__ u0, const __bf16* __restrict__ wr,
    const float* __restrict__ thr, float* __restrict__ out) {
  __shared__ __align__(16) __bf16 a_s[128][136];
  int tid = threadIdx.x;
  int lane = tid & 63, wv = tid >> 6;       // wv 0..3
  int l15 = lane & 15, quad = lane >> 4;
  int n0 = wv * 32 + l15;                   // tile0 row (local px)
  int n1 = n0 + 16;                         // tile1 row
  size_t p0 = (size_t)blockIdx.x * 128 + n0;
  size_t p1 = p0 + 16;
  int pb0 = (int)(p0 / (HO * WO)), pr0 = (int)(p0 % (HO * WO));
  int pb1 = (int)(p1 / (HO * WO)), pr1 = (int)(p1 % (HO * WO));

  // -Wr A-fragments (persist): 8 mt x 4 kt = 32 VGPRs
  bf16x8 Af[8][4];
#pragma unroll
  for (int mt = 0; mt < 8; ++mt) {
    int m = mt * 16 + l15;
#pragma unroll
    for (int kt = 0; kt < 4; ++kt)
      Af[mt][kt] = *(const bf16x8*)&wr[(size_t)m * COUT + kt * 32 + quad * 8];
  }
  // u0 - thr fragments (C-layout) for both tiles
  f32x4 u0f0[8], u0f1[8];
#pragma unroll
  for (int mt = 0; mt < 8; ++mt) {
    f32x4 t = *(const f32x4*)&thr[mt * 16 + quad * 4];
    u0f0[mt] = *(const f32x4*)&u0[p0 * COUT + mt * 16 + quad * 4] - t;
    u0f1[mt] = *(const f32x4*)&u0[p1 * COUT + mt * 16 + quad * 4] - t;
  }
  // a_0 = relu(u0 - thr) -> LDS
#pragma unroll
  for (int mt = 0; mt < 8; ++mt) {
    bf16x4 k0, k1;
#pragma unroll
    for (int r = 0; r < 4; ++r) {
      k0[r] = (__bf16)fmaxf(u0f0[mt][r], 0.f);
      k1[r] = (__bf16)fmaxf(u0f1[mt][r], 0.f);
    }
    *(bf16x4*)&a_s[n0][mt * 16 + quad * 4] = k0;
    *(bf16x4*)&a_s[n1][mt * 16 + quad * 4] = k1;
  }
#pragma unroll 1
  for (int it = 0; it < NITER; ++it) {
    bf16x8 B0[4], B1[4];
#pragma unroll
    for (int kt = 0; kt < 4; ++kt) {
      B0[kt] = *(const bf16x8*)&a_s[n0][kt * 32 + quad * 8];
      B1[kt] = *(const bf16x8*)&a_s[n1][kt * 32 + quad * 8];
    }
#pragma unroll
    for (int mt = 0; mt < 8; ++mt) {
      f32x4 a0 = u0f0[mt], a1 = u0f1[mt];
#pragma unroll
      for (int kt = 0; kt < 4; ++kt) {
        a0 = __builtin_amdgcn_mfma_f32_16x16x32_bf16(Af[mt][kt], B0[kt], a0, 0, 0, 0);
        a1 = __builtin_amdgcn_mfma_f32_16x16x32_bf16(Af[mt][kt], B1[kt], a1, 0, 0, 0);
      }
      bf16x4 k0, k1;
#pragma unroll
      for (int r = 0; r < 4; ++r) {
        k0[r] = (__bf16)fmaxf(a0[r], 0.f);
        k1[r] = (__bf16)fmaxf(a1[r], 0.f);
      }
      *(bf16x4*)&a_s[n0][mt * 16 + quad * 4] = k0;
      *(bf16x4*)&a_s[n1][mt * 16 + quad * 4] = k1;
    }
  }
  // final matvec -> relu -> NCHW global store
  {
    bf16x8 B0[4], B1[4];
#pragma unroll
    for (int kt = 0; kt < 4; ++kt) {
      B0[kt] = *(const bf16x8*)&a_s[n0][kt * 32 + quad * 8];
      B1[kt] = *(const bf16x8*)&a_s[n1][kt * 32 + quad * 8];
    }
#pragma unroll
    for (int mt = 0; mt < 8; ++mt) {
      f32x4 a0 = u0f0[mt], a1 = u0f1[mt];
#pragma unroll
      for (int kt = 0; kt < 4; ++kt) {
        a0 = __builtin_amdgcn_mfma_f32_16x16x32_bf16(Af[mt][kt], B0[kt], a0, 0, 0, 0);
        a1 = __builtin_amdgcn_mfma_f32_16x16x32_bf16(Af[mt][kt], B1[kt], a1, 0, 0, 0);
      }
#pragma unroll
      for (int r = 0; r < 4; ++r) {
        int ch = mt * 16 + quad * 4 + r;
        out[((size_t)pb0 * COUT + ch) * (HO * WO) + pr0] = fmaxf(a0[r], 0.f);
        out[((size_t)pb1 * COUT + ch) * (HO * WO) + pr1] = fmaxf(a1[r], 0.f);
      }
    }
  }
}

// ---------------------------------------------------------------------------
extern "C" void kernel_launch(void* const* d_in, const int* in_sizes, int n_in,
                              void* d_out, int out_size, void* d_ws, size_t ws_size,
                              hipStream_t stream) {
  const float* x    = (const float*)d_in[0];   // (64,64,64,64)
  const float* wff  = (const float*)d_in[1];   // (128,64,3,3)
  const float* wrec = (const float*)d_in[2];   // (128,128,1,1)
  const float* thr  = (const float*)d_in[3];   // (128,)
  float* out = (float*)d_out;                  // (64,128,62,62)

  char* ws = (char*)d_ws;
  size_t off = 0;
  float*  u0 = (float*)(ws + off);  off += (size_t)NPIX * COUT * 4;          // 126 MB
  __bf16* xh = (__bf16*)(ws + off); off += (size_t)B_ * HIN * WIN * CIN * 2; // 33.6 MB
  __bf16* wt = (__bf16*)(ws + off); off += (size_t)9 * COUT * CIN * 2;       // 147 KB
  __bf16* wr = (__bf16*)(ws + off); off += (size_t)COUT * COUT * 2;          // 32 KB

  prep_w_kernel<<<352, 256, 0, stream>>>(wff, wrec, wt, wr);
  prep_x_kernel<<<B_ * HIN, 256, 0, stream>>>(x, xh);
  conv_kernel<<<dim3(16, B_), 256, 0, stream>>>(xh, wt, u0);
  iterate_kernel<<<NPIX / 128, 256, 0, stream>>>(u0, wr, thr, out);
}

// Round 5
// 394.615 us; speedup vs baseline: 1.4943x; 1.4943x over previous
//
#include <hip/hip_runtime.h>
#include <hip/hip_bf16.h>

typedef __bf16 bf16x8 __attribute__((ext_vector_type(8)));
typedef __bf16 bf16x4 __attribute__((ext_vector_type(4)));
typedef float  f32x4  __attribute__((ext_vector_type(4)));
typedef float  f32x16 __attribute__((ext_vector_type(16)));

#define B_    64
#define CIN   64
#define HIN   64
#define WIN   64
#define COUT  128
#define HO    62
#define WO    62
#define NPIX  (B_*H O*WO)
#undef NPIX
#define NPIX  (B_*HO*WO)        /* 246016 = 1922*128 exactly */
#define NITER 13                /* LDS rounds; +1 final matvec = 14 total */

// Pin a value into VGPRs: non-rematerializable, forces true residency.
#define PIN(x) asm volatile("" : "+v"(x))

// ---------------------------------------------------------------------------
// prep_w: W_ff -> wt[tap][o][c] bf16 ; W_rec -> wr[o][c] = NEGATED bf16
// ---------------------------------------------------------------------------
__global__ void prep_w_kernel(const float* __restrict__ wff,
                              const float* __restrict__ wrec,
                              __bf16* __restrict__ wt,
                              __bf16* __restrict__ wr) {
  int i = blockIdx.x * 256 + threadIdx.x;
  const int NW = 9 * COUT * CIN;            // 73728
  if (i < NW) {
    int tap = i / (COUT * CIN);
    int rem = i % (COUT * CIN);
    int o = rem >> 6;
    int c = rem & 63;
    int kh = tap / 3, kw = tap % 3;
    wt[i] = (__bf16)wff[((o * CIN + c) * 3 + kh) * 3 + kw];
  } else {
    int j = i - NW;
    if (j < COUT * COUT) wr[j] = (__bf16)(-wrec[j]);
  }
}

// ---------------------------------------------------------------------------
// prep_x: x NCHW fp32 -> bf16, layout [b][h][c>>3][w][c&7]
// ---------------------------------------------------------------------------
__global__ void prep_x_kernel(const float* __restrict__ x,
                              __bf16* __restrict__ xh) {
  __shared__ float t[64][65];
  int tid = threadIdx.x;
  int b = blockIdx.x >> 6;
  int h = blockIdx.x & 63;
#pragma unroll
  for (int it = 0; it < 16; ++it) {
    int c = it * 4 + (tid >> 6);
    int w = tid & 63;
    t[c][w] = x[(((size_t)(b * 64 + c)) * 64 + h) * 64 + w];
  }
  __syncthreads();
  size_t rowbase = (size_t)blockIdx.x * 4096;
#pragma unroll
  for (int it = 0; it < 16; ++it) {
    int j = it * 256 + tid;
    int c8  = j & 7;
    int w   = (j >> 3) & 63;
    int grp = j >> 9;
    xh[rowbase + j] = (__bf16)t[grp * 8 + c8][w];
  }
}

// ---------------------------------------------------------------------------
// conv: persistent-weight implicit GEMM, 32x32x16 bf16 MFMA.
// Wf (144 VGPRs) PINNED in registers -> zero weight traffic in the loop.
// ---------------------------------------------------------------------------
__global__ __launch_bounds__(256, 2) void conv_kernel(
    const __bf16* __restrict__ xh, const __bf16* __restrict__ wt,
    float* __restrict__ u0) {
  // layout [row 6][grp 8][w 64][c8 8] = 24576 el = 48KB, flat == global order
  __shared__ __align__(16) __bf16 xs[6 * 8 * 64 * 8];
  int tid  = threadIdx.x;
  int lane = tid & 63;
  int wv   = tid >> 6;                      // 0..3 : c_out slice
  int hg   = blockIdx.x;                    // 0..15 : output-row group (4 rows)
  int b    = blockIdx.y;

  // ---- stage 6 input rows (hg*4 .. hg*4+5, clamped) ----
#pragma unroll
  for (int i = 0; i < 12; ++i) {
    int chunk = wv * 12 + i;                // 0..47
    int row = chunk >> 3;
    int part = chunk & 7;
    int row_src = hg * 4 + row;
    if (row_src > 63) row_src = 63;
    const __bf16* g = xh + ((size_t)(b * 64 + row_src)) * 4096 + part * 512 + lane * 8;
    __bf16* l = xs + chunk * 512;
    __builtin_amdgcn_global_load_lds(
        (const __attribute__((address_space(1))) void*)g,
        (__attribute__((address_space(3))) void*)l, 16, 0, 0);
  }

  // ---- this wave's full weight set -> registers, PINNED ----
  int m31 = lane & 31;
  int khalf = lane >> 5;                    // A[m][k]: m=lane&31, k=khalf*8+j
  bf16x8 Wf[36];
#pragma unroll
  for (int tap = 0; tap < 9; ++tap)
#pragma unroll
    for (int k4 = 0; k4 < 4; ++k4)
      Wf[tap * 4 + k4] = *(const bf16x8*)
          &wt[((size_t)tap * COUT + wv * 32 + m31) * CIN + k4 * 16 + khalf * 8];
#pragma unroll
  for (int i = 0; i < 36; ++i) PIN(Wf[i]);

  __syncthreads();

  // ---- 8 n-tiles of 32 pixels ----
#pragma unroll 1
  for (int nt = 0; nt < 8; ++nt) {
    int px = nt * 32 + m31;                 // local pixel 0..255 (248 valid)
    int r = (px >= 62) + (px >= 124) + (px >= 186) + (px >= 248);
    if (r > 3) r = 3;
    int wcol = px - r * 62;
    if (wcol > 61) wcol = 61;
    int orow = hg * 4 + r;
    bool valid = (px < 248) && (orow < 62);
    const char* lbase = (const char*)xs + (((r * 8 + khalf) * 64 + wcol) << 4);

    f32x16 acc0, acc1;
#pragma unroll
    for (int q = 0; q < 16; ++q) { acc0[q] = 0.f; acc1[q] = 0.f; }

#pragma unroll
    for (int tap = 0; tap < 9; ++tap) {
      int kh = tap / 3, kw = tap % 3;
#pragma unroll
      for (int k4 = 0; k4 < 4; ++k4) {
        bf16x8 Bf = *(const bf16x8*)(lbase + kh * 8192 + k4 * 2048 + kw * 16);
        int idx = tap * 4 + k4;
        if (idx & 1) acc1 = __builtin_amdgcn_mfma_f32_32x32x16_bf16(Wf[idx], Bf, acc1, 0, 0, 0);
        else         acc0 = __builtin_amdgcn_mfma_f32_32x32x16_bf16(Wf[idx], Bf, acc0, 0, 0, 0);
      }
    }
    if (valid) {
      size_t pix = ((size_t)b * HO + orow) * WO + wcol;
      // C/D layout 32x32: col=lane&31, row=(reg&3)+8*(reg>>2)+4*khalf
      float* up = u0 + pix * COUT + wv * 32 + khalf * 4;
#pragma unroll
      for (int g4 = 0; g4 < 4; ++g4) {
        f32x4 v;
#pragma unroll
        for (int q = 0; q < 4; ++q) v[q] = acc0[g4 * 4 + q] + acc1[g4 * 4 + q];
        *(f32x4*)&up[g4 * 8] = v;
      }
    }
  }
}

// ---------------------------------------------------------------------------
// iterate: 14 undamped Picard steps on-chip. 512 thr = 8 waves; wave owns
// M=128 (all channels) x N=16 pixels. -Wr A-frags (128 VGPRs) PINNED in
// registers; only a (bf16) round-trips through LDS. No barriers: each wave
// reads/writes only its own 16 LDS rows.
// ---------------------------------------------------------------------------
__global__ __launch_bounds__(512, 2) void iterate_kernel(
    const float* __restrict__ u0, const __bf16* __restrict__ wr,
    const float* __restrict__ thr, float* __restrict__ out) {
  __shared__ __align__(16) __bf16 a_s[128][136];
  int tid = threadIdx.x;
  int lane = tid & 63, wv = tid >> 6;
  int l15 = lane & 15, quad = lane >> 4;
  int nloc = wv * 16 + l15;                 // this lane's pixel (col)
  size_t p = (size_t)blockIdx.x * 128 + nloc;
  int pb = (int)(p / (HO * WO));            // batch  (for NCHW store)
  int pr = (int)(p % (HO * WO));            // h*62+w

  // -Wr A-fragments, PINNED: 8 mt x 4 kt = 128 VGPRs
  bf16x8 Af[8][4];
#pragma unroll
  for (int mt = 0; mt < 8; ++mt) {
    int m = mt * 16 + l15;
#pragma unroll
    for (int kt = 0; kt < 4; ++kt)
      Af[mt][kt] = *(const bf16x8*)&wr[(size_t)m * COUT + kt * 32 + quad * 8];
  }
#pragma unroll
  for (int mt = 0; mt < 8; ++mt)
#pragma unroll
    for (int kt = 0; kt < 4; ++kt) PIN(Af[mt][kt]);

  // u0 - thr fragments (C-layout), PINNED
  f32x4 u0f[8];
#pragma unroll
  for (int mt = 0; mt < 8; ++mt) {
    f32x4 u = *(const f32x4*)&u0[p * COUT + mt * 16 + quad * 4];
    f32x4 t = *(const f32x4*)&thr[mt * 16 + quad * 4];
    u0f[mt] = u - t;
  }
#pragma unroll
  for (int mt = 0; mt < 8; ++mt) PIN(u0f[mt]);

  // a_0 = relu(u0 - thr) -> LDS (bf16), C-layout positions
#pragma unroll
  for (int mt = 0; mt < 8; ++mt) {
    bf16x4 pk;
#pragma unroll
    for (int r = 0; r < 4; ++r) pk[r] = (__bf16)fmaxf(u0f[mt][r], 0.f);
    *(bf16x4*)&a_s[nloc][mt * 16 + quad * 4] = pk;
  }
#pragma unroll 1
  for (int it = 0; it < NITER; ++it) {
    bf16x8 Bf[4];
#pragma unroll
    for (int kt = 0; kt < 4; ++kt)
      Bf[kt] = *(const bf16x8*)&a_s[nloc][kt * 32 + quad * 8];
#pragma unroll
    for (int mt = 0; mt < 8; ++mt) {
      f32x4 a = u0f[mt];                    // acc init = u0-thr; Wr negated
#pragma unroll
      for (int kt = 0; kt < 4; ++kt)
        a = __builtin_amdgcn_mfma_f32_16x16x32_bf16(Af[mt][kt], Bf[kt], a, 0, 0, 0);
      bf16x4 pk;
#pragma unroll
      for (int r = 0; r < 4; ++r) pk[r] = (__bf16)fmaxf(a[r], 0.f);
      *(bf16x4*)&a_s[nloc][mt * 16 + quad * 4] = pk;
    }
  }
  // final matvec -> relu -> NCHW global store
  {
    bf16x8 Bf[4];
#pragma unroll
    for (int kt = 0; kt < 4; ++kt)
      Bf[kt] = *(const bf16x8*)&a_s[nloc][kt * 32 + quad * 8];
#pragma unroll
    for (int mt = 0; mt < 8; ++mt) {
      f32x4 a = u0f[mt];
#pragma unroll
      for (int kt = 0; kt < 4; ++kt)
        a = __builtin_amdgcn_mfma_f32_16x16x32_bf16(Af[mt][kt], Bf[kt], a, 0, 0, 0);
#pragma unroll
      for (int r = 0; r < 4; ++r) {
        int ch = mt * 16 + quad * 4 + r;
        out[((size_t)pb * COUT + ch) * (HO * WO) + pr] = fmaxf(a[r], 0.f);
      }
    }
  }
}

// ---------------------------------------------------------------------------
extern "C" void kernel_launch(void* const* d_in, const int* in_sizes, int n_in,
                              void* d_out, int out_size, void* d_ws, size_t ws_size,
                              hipStream_t stream) {
  const float* x    = (const float*)d_in[0];   // (64,64,64,64)
  const float* wff  = (const float*)d_in[1];   // (128,64,3,3)
  const float* wrec = (const float*)d_in[2];   // (128,128,1,1)
  const float* thr  = (const float*)d_in[3];   // (128,)
  float* out = (float*)d_out;                  // (64,128,62,62)

  char* ws = (char*)d_ws;
  size_t off = 0;
  float*  u0 = (float*)(ws + off);  off += (size_t)NPIX * COUT * 4;          // 126 MB
  __bf16* xh = (__bf16*)(ws + off); off += (size_t)B_ * HIN * WIN * CIN * 2; // 33.6 MB
  __bf16* wt = (__bf16*)(ws + off); off += (size_t)9 * COUT * CIN * 2;       // 147 KB
  __bf16* wr = (__bf16*)(ws + off); off += (size_t)COUT * COUT * 2;          // 32 KB

  prep_w_kernel<<<352, 256, 0, stream>>>(wff, wrec, wt, wr);
  prep_x_kernel<<<B_ * HIN, 256, 0, stream>>>(x, xh);
  conv_kernel<<<dim3(16, B_), 256, 0, stream>>>(xh, wt, u0);
  iterate_kernel<<<NPIX / 128, 512, 0, stream>>>(u0, wr, thr, out);
}

// Round 6
// 371.219 us; speedup vs baseline: 1.5884x; 1.0630x over previous
//
#include <hip/hip_runtime.h>
#include <hip/hip_bf16.h>

typedef __bf16 bf16x8 __attribute__((ext_vector_type(8)));
typedef __bf16 bf16x4 __attribute__((ext_vector_type(4)));
typedef float  f32x4  __attribute__((ext_vector_type(4)));
typedef float  f32x16 __attribute__((ext_vector_type(16)));

#define B_    64
#define CIN   64
#define HIN   64
#define WIN   64
#define COUT  128
#define HO    62
#define WO    62
#define NPIX  (B_*HO*WO)        /* 246016 = 1922*128 exactly */
#define NITER 10                /* LDS rounds; +1 final matvec = 11 total */

// Pin a matrix fragment into AGPRs. gfx950 MFMA reads A/B straight from
// AGPRs, so this forces true residency (no per-iteration L1/L2 reload)
// without consuming arch-VGPR budget. "+v" (R5) was a no-op: allocator
// only had to touch a VGPR at the asm site, then went back to reloading.
#define PIN_A(x) asm volatile("" : "+a"(x))
#define PIN_V(x) asm volatile("" : "+v"(x))

// ---------------------------------------------------------------------------
// prep_w: W_ff -> wt[tap][o][c] bf16 ; W_rec -> wr[o][c] = NEGATED bf16
// ---------------------------------------------------------------------------
__global__ void prep_w_kernel(const float* __restrict__ wff,
                              const float* __restrict__ wrec,
                              __bf16* __restrict__ wt,
                              __bf16* __restrict__ wr) {
  int i = blockIdx.x * 256 + threadIdx.x;
  const int NW = 9 * COUT * CIN;            // 73728
  if (i < NW) {
    int tap = i / (COUT * CIN);
    int rem = i % (COUT * CIN);
    int o = rem >> 6;
    int c = rem & 63;
    int kh = tap / 3, kw = tap % 3;
    wt[i] = (__bf16)wff[((o * CIN + c) * 3 + kh) * 3 + kw];
  } else {
    int j = i - NW;
    if (j < COUT * COUT) wr[j] = (__bf16)(-wrec[j]);
  }
}

// ---------------------------------------------------------------------------
// prep_x: x NCHW fp32 -> bf16, layout [b][h][c>>3][w][c&7]
// ---------------------------------------------------------------------------
__global__ void prep_x_kernel(const float* __restrict__ x,
                              __bf16* __restrict__ xh) {
  __shared__ float t[64][65];
  int tid = threadIdx.x;
  int b = blockIdx.x >> 6;
  int h = blockIdx.x & 63;
#pragma unroll
  for (int it = 0; it < 16; ++it) {
    int c = it * 4 + (tid >> 6);
    int w = tid & 63;
    t[c][w] = x[(((size_t)(b * 64 + c)) * 64 + h) * 64 + w];
  }
  __syncthreads();
  size_t rowbase = (size_t)blockIdx.x * 4096;
#pragma unroll
  for (int it = 0; it < 16; ++it) {
    int j = it * 256 + tid;
    int c8  = j & 7;
    int w   = (j >> 3) & 63;
    int grp = j >> 9;
    xh[rowbase + j] = (__bf16)t[grp * 8 + c8][w];
  }
}

// ---------------------------------------------------------------------------
// conv: persistent-weight implicit GEMM, 32x32x16 bf16 MFMA.
// Wf (144 regs) pinned into AGPRs -> zero weight traffic in the nt loop.
// ---------------------------------------------------------------------------
__global__ __launch_bounds__(256, 2) void conv_kernel(
    const __bf16* __restrict__ xh, const __bf16* __restrict__ wt,
    float* __restrict__ u0) {
  // layout [row 6][grp 8][w 64][c8 8] = 24576 el = 48KB, flat == global order
  __shared__ __align__(16) __bf16 xs[6 * 8 * 64 * 8];
  int tid  = threadIdx.x;
  int lane = tid & 63;
  int wv   = tid >> 6;                      // 0..3 : c_out slice
  int hg   = blockIdx.x;                    // 0..15 : output-row group (4 rows)
  int b    = blockIdx.y;

  // ---- stage 6 input rows (hg*4 .. hg*4+5, clamped) ----
#pragma unroll
  for (int i = 0; i < 12; ++i) {
    int chunk = wv * 12 + i;                // 0..47
    int row = chunk >> 3;
    int part = chunk & 7;
    int row_src = hg * 4 + row;
    if (row_src > 63) row_src = 63;
    const __bf16* g = xh + ((size_t)(b * 64 + row_src)) * 4096 + part * 512 + lane * 8;
    __bf16* l = xs + chunk * 512;
    __builtin_amdgcn_global_load_lds(
        (const __attribute__((address_space(1))) void*)g,
        (__attribute__((address_space(3))) void*)l, 16, 0, 0);
  }

  // ---- this wave's full weight set -> AGPRs (loaded once, resident) ----
  int m31 = lane & 31;
  int khalf = lane >> 5;                    // A[m][k]: m=lane&31, k=khalf*8+j
  bf16x8 Wf[36];
#pragma unroll
  for (int tap = 0; tap < 9; ++tap)
#pragma unroll
    for (int k4 = 0; k4 < 4; ++k4)
      Wf[tap * 4 + k4] = *(const bf16x8*)
          &wt[((size_t)tap * COUT + wv * 32 + m31) * CIN + k4 * 16 + khalf * 8];
#pragma unroll
  for (int i = 0; i < 36; ++i) PIN_A(Wf[i]);

  __syncthreads();

  // ---- 8 n-tiles of 32 pixels ----
#pragma unroll 1
  for (int nt = 0; nt < 8; ++nt) {
    int px = nt * 32 + m31;                 // local pixel 0..255 (248 valid)
    int r = (px >= 62) + (px >= 124) + (px >= 186) + (px >= 248);
    if (r > 3) r = 3;
    int wcol = px - r * 62;
    if (wcol > 61) wcol = 61;
    int orow = hg * 4 + r;
    bool valid = (px < 248) && (orow < 62);
    const char* lbase = (const char*)xs + (((r * 8 + khalf) * 64 + wcol) << 4);

    f32x16 acc0, acc1;
#pragma unroll
    for (int q = 0; q < 16; ++q) { acc0[q] = 0.f; acc1[q] = 0.f; }

#pragma unroll
    for (int tap = 0; tap < 9; ++tap) {
      int kh = tap / 3, kw = tap % 3;
#pragma unroll
      for (int k4 = 0; k4 < 4; ++k4) {
        bf16x8 Bf = *(const bf16x8*)(lbase + kh * 8192 + k4 * 2048 + kw * 16);
        int idx = tap * 4 + k4;
        if (idx & 1) acc1 = __builtin_amdgcn_mfma_f32_32x32x16_bf16(Wf[idx], Bf, acc1, 0, 0, 0);
        else         acc0 = __builtin_amdgcn_mfma_f32_32x32x16_bf16(Wf[idx], Bf, acc0, 0, 0, 0);
      }
    }
    if (valid) {
      size_t pix = ((size_t)b * HO + orow) * WO + wcol;
      // C/D layout 32x32: col=lane&31, row=(reg&3)+8*(reg>>2)+4*khalf
      float* up = u0 + pix * COUT + wv * 32 + khalf * 4;
#pragma unroll
      for (int g4 = 0; g4 < 4; ++g4) {
        f32x4 v;
#pragma unroll
        for (int q = 0; q < 4; ++q) v[q] = acc0[g4 * 4 + q] + acc1[g4 * 4 + q];
        *(f32x4*)&up[g4 * 8] = v;
      }
    }
  }
}

// ---------------------------------------------------------------------------
// iterate: 11 undamped Picard matvecs on-chip. 512 thr = 8 waves; wave owns
// M=128 (all channels) x N=16 pixels. -Wr A-frags (128 regs) pinned in
// AGPRs (MFMA reads A from AGPR natively); only a (bf16) round-trips
// through LDS. No barriers: wave touches only its own 16 LDS rows.
// ---------------------------------------------------------------------------
__global__ __launch_bounds__(512, 2) void iterate_kernel(
    const float* __restrict__ u0, const __bf16* __restrict__ wr,
    const float* __restrict__ thr, float* __restrict__ out) {
  __shared__ __align__(16) __bf16 a_s[128][136];
  int tid = threadIdx.x;
  int lane = tid & 63, wv = tid >> 6;
  int l15 = lane & 15, quad = lane >> 4;
  int nloc = wv * 16 + l15;                 // this lane's pixel (col)
  size_t p = (size_t)blockIdx.x * 128 + nloc;
  int pb = (int)(p / (HO * WO));            // batch  (for NCHW store)
  int pr = (int)(p % (HO * WO));            // h*62+w

  // -Wr A-fragments -> AGPRs: 8 mt x 4 kt = 128 regs, resident for kernel
  bf16x8 Af[8][4];
#pragma unroll
  for (int mt = 0; mt < 8; ++mt) {
    int m = mt * 16 + l15;
#pragma unroll
    for (int kt = 0; kt < 4; ++kt)
      Af[mt][kt] = *(const bf16x8*)&wr[(size_t)m * COUT + kt * 32 + quad * 8];
  }
#pragma unroll
  for (int mt = 0; mt < 8; ++mt)
#pragma unroll
    for (int kt = 0; kt < 4; ++kt) PIN_A(Af[mt][kt]);

  // u0 - thr fragments (C-layout), VGPR-resident
  f32x4 u0f[8];
#pragma unroll
  for (int mt = 0; mt < 8; ++mt) {
    f32x4 u = *(const f32x4*)&u0[p * COUT + mt * 16 + quad * 4];
    f32x4 t = *(const f32x4*)&thr[mt * 16 + quad * 4];
    u0f[mt] = u - t;
  }
#pragma unroll
  for (int mt = 0; mt < 8; ++mt) PIN_V(u0f[mt]);

  // a_0 = relu(u0 - thr) -> LDS (bf16), C-layout positions
#pragma unroll
  for (int mt = 0; mt < 8; ++mt) {
    bf16x4 pk;
#pragma unroll
    for (int r = 0; r < 4; ++r) pk[r] = (__bf16)fmaxf(u0f[mt][r], 0.f);
    *(bf16x4*)&a_s[nloc][mt * 16 + quad * 4] = pk;
  }
#pragma unroll 1
  for (int it = 0; it < NITER; ++it) {
    bf16x8 Bf[4];
#pragma unroll
    for (int kt = 0; kt < 4; ++kt)
      Bf[kt] = *(const bf16x8*)&a_s[nloc][kt * 32 + quad * 8];
#pragma unroll
    for (int mt = 0; mt < 8; ++mt) {
      f32x4 a = u0f[mt];                    // acc init = u0-thr; Wr negated
#pragma unroll
      for (int kt = 0; kt < 4; ++kt)
        a = __builtin_amdgcn_mfma_f32_16x16x32_bf16(Af[mt][kt], Bf[kt], a, 0, 0, 0);
      bf16x4 pk;
#pragma unroll
      for (int r = 0; r < 4; ++r) pk[r] = (__bf16)fmaxf(a[r], 0.f);
      *(bf16x4*)&a_s[nloc][mt * 16 + quad * 4] = pk;
    }
  }
  // final matvec -> relu -> NCHW global store
  {
    bf16x8 Bf[4];
#pragma unroll
    for (int kt = 0; kt < 4; ++kt)
      Bf[kt] = *(const bf16x8*)&a_s[nloc][kt * 32 + quad * 8];
#pragma unroll
    for (int mt = 0; mt < 8; ++mt) {
      f32x4 a = u0f[mt];
#pragma unroll
      for (int kt = 0; kt < 4; ++kt)
        a = __builtin_amdgcn_mfma_f32_16x16x32_bf16(Af[mt][kt], Bf[kt], a, 0, 0, 0);
#pragma unroll
      for (int r = 0; r < 4; ++r) {
        int ch = mt * 16 + quad * 4 + r;
        out[((size_t)pb * COUT + ch) * (HO * WO) + pr] = fmaxf(a[r], 0.f);
      }
    }
  }
}

// ---------------------------------------------------------------------------
extern "C" void kernel_launch(void* const* d_in, const int* in_sizes, int n_in,
                              void* d_out, int out_size, void* d_ws, size_t ws_size,
                              hipStream_t stream) {
  const float* x    = (const float*)d_in[0];   // (64,64,64,64)
  const float* wff  = (const float*)d_in[1];   // (128,64,3,3)
  const float* wrec = (const float*)d_in[2];   // (128,128,1,1)
  const float* thr  = (const float*)d_in[3];   // (128,)
  float* out = (float*)d_out;                  // (64,128,62,62)

  char* ws = (char*)d_ws;
  size_t off = 0;
  float*  u0 = (float*)(ws + off);  off += (size_t)NPIX * COUT * 4;          // 126 MB
  __bf16* xh = (__bf16*)(ws + off); off += (size_t)B_ * HIN * WIN * CIN * 2; // 33.6 MB
  __bf16* wt = (__bf16*)(ws + off); off += (size_t)9 * COUT * CIN * 2;       // 147 KB
  __bf16* wr = (__bf16*)(ws + off); off += (size_t)COUT * COUT * 2;          // 32 KB

  prep_w_kernel<<<352, 256, 0, stream>>>(wff, wrec, wt, wr);
  prep_x_kernel<<<B_ * HIN, 256, 0, stream>>>(x, xh);
  conv_kernel<<<dim3(16, B_), 256, 0, stream>>>(xh, wt, u0);
  iterate_kernel<<<NPIX / 128, 512, 0, stream>>>(u0, wr, thr, out);
}